// Round 6
// baseline (840.624 us; speedup 1.0000x reference)
//
#include <hip/hip_runtime.h>
#include <stdint.h>

#define Q_INV (1.0f / 128.0f)

__device__ __forceinline__ float quant_comp_f(float v) {
    float f = floorf(v * 128.0f);
    f = fminf(fmaxf(f, -128.0f), 127.0f);
    int qi = (int)f;
    qi |= 1;
    return (float)qi * Q_INV;
}

__device__ __forceinline__ int quant_q(float v) {
    float f = floorf(v * 128.0f);
    f = fminf(fmaxf(f, -128.0f), 127.0f);
    return ((int)f) | 1;   // -128|1 = -127; all values fit int8, odd
}

// ---------------- prep: quantize x to int8, transpose/prescale weights ----
__global__ __launch_bounds__(256) void prep_kernel(
    const float* __restrict__ x, const float* __restrict__ c1w,
    const float* __restrict__ c2w, const float* __restrict__ w1,
    const float* __restrict__ w2, const float* __restrict__ w3,
    int8_t* __restrict__ xq8, float* __restrict__ c1ws, float* __restrict__ c2ws,
    float* __restrict__ w1t, float* __restrict__ w2t, float* __restrict__ w3t,
    int N)
{
    const int bid = blockIdx.x, t = threadIdx.x;
    if (bid < 4096) {
        for (int i = bid * 256 + t; i < N; i += 4096 * 256)
            xq8[i] = (int8_t)quant_q(x[i]);
    } else if (bid == 4096) {
        for (int i = t; i < 150; i += 256) c1ws[i] = c1w[i] * Q_INV;
        for (int i = t; i < 2400; i += 256) c2ws[i] = c2w[i] * Q_INV;
    } else if (bid == 4097) {
        for (int i = t; i < 48000; i += 256) {
            const int k = i / 120, o = i % 120;
            w1t[i] = w1[o * 400 + k] * Q_INV;
        }
    } else {
        for (int i = t; i < 10080; i += 256) {
            const int k = i / 84, o = i % 84;
            w2t[i] = w2[o * 120 + k] * Q_INV;
        }
        for (int i = t; i < 840; i += 256) {
            const int k = i / 10, o = i % 10;
            w3t[i] = w3[o * 84 + k];   // fc3 input is dequantized f32
        }
    }
}

// ---------------- conv1: lane=image, item=(c-pair, pooled-row) -------------
// chain per output: ky asc, kx asc (zero-pad terms skipped: exact no-ops).
__global__ __launch_bounds__(256) void conv1_int8_kernel(
    const int8_t* __restrict__ xq8, const float* __restrict__ c1ws,
    const float* __restrict__ c1b, const int* __restrict__ qflag,
    int8_t* __restrict__ mid8, int G)
{
    if (qflag[0] == 0) return;
    const int t = threadIdx.x;
    const int W = blockIdx.x * 4 + (t >> 6);
    if (W >= G * 42) return;
    const int lane = t & 63;
    const int g = W / 42;
    const int item = W % 42;
    const int cp = item / 14;     // 0..2
    const int ph = item % 14;
    const int c0 = 2 * cp;

    const int8_t* xb = xq8 + (size_t)(g * 64 + lane) * 784;

    float wA[25], wB[25];
    #pragma unroll
    for (int k = 0; k < 25; ++k) {
        wA[k] = c1ws[c0 * 25 + k];
        wB[k] = c1ws[(c0 + 1) * 25 + k];
    }
    const float bA = c1b[c0], bB = c1b[c0 + 1];

    float hA[14], hB[14];

    #pragma unroll
    for (int oi = 0; oi < 2; ++oi) {
        const int oh = 2 * ph + oi;
        float aA[28], aB[28];
        #pragma unroll
        for (int j = 0; j < 28; ++j) { aA[j] = 0.0f; aB[j] = 0.0f; }
        #pragma unroll
        for (int ky = 0; ky < 5; ++ky) {
            const int ro = oh + ky - 2;
            if (ro >= 0 && ro < 28) {          // wave-uniform branch
                const int8_t* rp = xb + ro * 28;
                float rf[28];
                #pragma unroll
                for (int cc = 0; cc < 28; ++cc) rf[cc] = (float)(int)rp[cc];
                #pragma unroll
                for (int kx = 0; kx < 5; ++kx) {
                    const float va = wA[ky * 5 + kx];
                    const float vb = wB[ky * 5 + kx];
                    #pragma unroll
                    for (int ow = 0; ow < 28; ++ow) {
                        const int oc = ow + kx - 2;
                        if (oc >= 0 && oc < 28) {
                            aA[ow] = fmaf(rf[oc], va, aA[ow]);
                            aB[ow] = fmaf(rf[oc], vb, aB[ow]);
                        }
                    }
                }
            }
        }
        #pragma unroll
        for (int j = 0; j < 14; ++j) {
            float vA0 = aA[2 * j] + bA, vA1 = aA[2 * j + 1] + bA;
            float vB0 = aB[2 * j] + bB, vB1 = aB[2 * j + 1] + bB;
            float mA = fmaxf(vA0, vA1), mB = fmaxf(vB0, vB1);
            if (oi == 0) { hA[j] = mA; hB[j] = mB; }
            else {
                float fA = fmaxf(fmaxf(hA[j], mA), 0.0f);
                float fB = fmaxf(fmaxf(hB[j], mB), 0.0f);
                mid8[(size_t)g * 75264 + ((c0 * 14 + ph) * 14 + j) * 64 + lane] =
                    (int8_t)quant_q(fA);
                mid8[(size_t)g * 75264 + (((c0 + 1) * 14 + ph) * 14 + j) * 64 + lane] =
                    (int8_t)quant_q(fB);
            }
        }
    }
}

// ---------------- conv2: lane=image, item=(c-pair, pooled-row) -------------
// chain per output: ky asc (rr-streaming), kx asc, ic asc.
__global__ __launch_bounds__(256) void conv2_int8_kernel(
    const int8_t* __restrict__ mid8, const float* __restrict__ c2ws,
    const float* __restrict__ c2b, const int* __restrict__ qflag,
    int8_t* __restrict__ act8, int G)
{
    if (qflag[0] == 0) return;
    const int t = threadIdx.x;
    const int W = blockIdx.x * 4 + (t >> 6);
    if (W >= G * 40) return;
    const int lane = t & 63;
    const int g = W / 40;
    const int item = W % 40;
    const int cp = item / 5;      // 0..7
    const int ph = item % 5;
    const int c0 = 2 * cp;

    const int8_t* mb = mid8 + (size_t)g * 75264 + lane;

    float aA[2][10], aB[2][10];
    #pragma unroll
    for (int oi = 0; oi < 2; ++oi)
        #pragma unroll
        for (int j = 0; j < 10; ++j) { aA[oi][j] = 0.0f; aB[oi][j] = 0.0f; }

    #pragma unroll
    for (int rr = 0; rr < 6; ++rr) {
        const int r = 2 * ph + rr;
        float rf[6][14];
        #pragma unroll
        for (int ic = 0; ic < 6; ++ic) {
            const int8_t* mp = mb + (ic * 196 + r * 14) * 64;
            #pragma unroll
            for (int cc = 0; cc < 14; ++cc) rf[ic][cc] = (float)(int)mp[cc * 64];
        }
        #pragma unroll
        for (int oi = 0; oi < 2; ++oi) {
            const int ky = rr - oi;              // compile-time per (rr,oi)
            if (ky >= 0 && ky < 5) {
                #pragma unroll
                for (int kx = 0; kx < 5; ++kx) {
                    #pragma unroll
                    for (int ic = 0; ic < 6; ++ic) {
                        const float va = c2ws[(c0 * 6 + ic) * 25 + ky * 5 + kx];
                        const float vb = c2ws[((c0 + 1) * 6 + ic) * 25 + ky * 5 + kx];
                        #pragma unroll
                        for (int ow = 0; ow < 10; ++ow) {
                            aA[oi][ow] = fmaf(rf[ic][ow + kx], va, aA[oi][ow]);
                            aB[oi][ow] = fmaf(rf[ic][ow + kx], vb, aB[oi][ow]);
                        }
                    }
                }
            }
        }
    }

    const float bA = c2b[c0], bB = c2b[c0 + 1];
    int8_t* pa = act8 + (size_t)g * 25600 + (c0 * 25 + ph * 5) * 64 + lane;
    int8_t* pb = act8 + (size_t)g * 25600 + ((c0 + 1) * 25 + ph * 5) * 64 + lane;
    #pragma unroll
    for (int j = 0; j < 5; ++j) {
        float vA00 = aA[0][2 * j] + bA, vA01 = aA[0][2 * j + 1] + bA;
        float vA10 = aA[1][2 * j] + bA, vA11 = aA[1][2 * j + 1] + bA;
        float mA = fmaxf(fmaxf(vA00, vA01), fmaxf(vA10, vA11));
        mA = fmaxf(mA, 0.0f);
        pa[j * 64] = (int8_t)quant_q(mA);
        float vB00 = aB[0][2 * j] + bB, vB01 = aB[0][2 * j + 1] + bB;
        float vB10 = aB[1][2 * j] + bB, vB11 = aB[1][2 * j + 1] + bB;
        float mB = fmaxf(fmaxf(vB00, vB01), fmaxf(vB10, vB11));
        mB = fmaxf(mB, 0.0f);
        pb[j * 64] = (int8_t)quant_q(mB);
    }
}

// ---------------- fc1: lane=image, wave = 15 outputs ----------------------
__global__ __launch_bounds__(256) void fc1_int8_kernel(
    const int8_t* __restrict__ act8, const float* __restrict__ w1t,
    const float* __restrict__ b1, const int* __restrict__ qflag,
    int8_t* __restrict__ a18, int G)
{
    if (qflag[0] == 0) return;
    const int t = threadIdx.x;
    const int g = blockIdx.x >> 1;
    const int half = blockIdx.x & 1;
    const int w = t >> 6, lane = t & 63;
    const int o0 = half * 60 + w * 15;

    const int8_t* ab = act8 + (size_t)g * 25600 + lane;
    float acc[15];
    #pragma unroll
    for (int oo = 0; oo < 15; ++oo) acc[oo] = 0.0f;

    for (int kb = 0; kb < 25; ++kb) {
        const int8_t* ap = ab + kb * 16 * 64;
        #pragma unroll
        for (int kk = 0; kk < 16; ++kk) {
            const float a = (float)(int)ap[kk * 64];
            const int k = kb * 16 + kk;
            #pragma unroll
            for (int oo = 0; oo < 15; ++oo)
                acc[oo] = fmaf(a, w1t[k * 120 + o0 + oo], acc[oo]);
        }
    }
    int8_t* op = a18 + (size_t)g * 7680 + o0 * 64 + lane;
    #pragma unroll
    for (int oo = 0; oo < 15; ++oo) {
        float v = acc[oo] + b1[o0 + oo];
        v = fmaxf(v, 0.0f);
        op[oo * 64] = (int8_t)quant_q(v);
    }
}

// ---------------- fc2 + fc3 fused per image-group -------------------------
__global__ __launch_bounds__(256) void fc23_int8_kernel(
    const int8_t* __restrict__ a18, const float* __restrict__ w2t,
    const float* __restrict__ b2, const float* __restrict__ w3t,
    const float* __restrict__ b3, const int* __restrict__ qflag,
    float* __restrict__ out, int G)
{
    if (qflag[0] == 0) return;
    __shared__ float a2l[84][64];
    const int t = threadIdx.x;
    const int g = blockIdx.x;
    const int w = t >> 6, lane = t & 63;
    const int o0 = w * 21;

    const int8_t* ab = a18 + (size_t)g * 7680 + lane;
    float acc[21];
    #pragma unroll
    for (int oo = 0; oo < 21; ++oo) acc[oo] = 0.0f;

    for (int kb = 0; kb < 8; ++kb) {
        const int8_t* ap = ab + kb * 15 * 64;
        #pragma unroll
        for (int kk = 0; kk < 15; ++kk) {
            const float a = (float)(int)ap[kk * 64];
            const int k = kb * 15 + kk;
            #pragma unroll
            for (int oo = 0; oo < 21; ++oo)
                acc[oo] = fmaf(a, w2t[k * 84 + o0 + oo], acc[oo]);
        }
    }
    #pragma unroll
    for (int oo = 0; oo < 21; ++oo) {
        float v = acc[oo] + b2[o0 + oo];
        v = fmaxf(v, 0.0f);
        a2l[o0 + oo][lane] = (float)quant_q(v) * Q_INV;   // dequantized f32
    }
    __syncthreads();

    const int ob = w * 3;
    float a3[3] = {0.0f, 0.0f, 0.0f};
    for (int k = 0; k < 84; ++k) {
        const float a = a2l[k][lane];
        #pragma unroll
        for (int oo = 0; oo < 3; ++oo)
            if (ob + oo < 10) a3[oo] = fmaf(a, w3t[k * 10 + ob + oo], a3[oo]);
    }
    float* po = out + (size_t)(g * 64 + lane) * 10;
    #pragma unroll
    for (int oo = 0; oo < 3; ++oo)
        if (ob + oo < 10) po[ob + oo] = a3[oo] + b3[ob + oo];
}

// ================= R4 fallback pair (verified) — gate: 1 = only if q==0 ===
__global__ __launch_bounds__(256) void conv_fused_kernel(
    const float* __restrict__ x,
    const float* __restrict__ c1w, const float* __restrict__ c1b,
    const float* __restrict__ c2w, const float* __restrict__ c2b,
    const int* __restrict__ qflag,
    float* __restrict__ act, int gate)
{
    if (gate != 0 && qflag[0] != 0) return;
    __shared__ float pin[32][33];
    __shared__ float w1[6][25];
    __shared__ float b1s[6];
    __shared__ float mid[6][14][18];
    __shared__ float w2[2400];
    __shared__ float b2s[16];

    const int t = threadIdx.x;
    const int img = blockIdx.x;
    const bool q = (qflag[0] != 0);

    for (int i = t; i < 32 * 33; i += 256) (&pin[0][0])[i] = 0.0f;
    for (int i = t; i < 6 * 14 * 18; i += 256) (&mid[0][0][0])[i] = 0.0f;
    if (t < 150) (&w1[0][0])[t] = c1w[t];
    if (t < 6) b1s[t] = c1b[t];
    for (int i = t; i < 2400; i += 256) w2[i] = c2w[i];
    if (t < 16) b2s[t] = c2b[t];
    __syncthreads();

    const float* xi = x + (size_t)img * 784;
    for (int i = t; i < 784; i += 256) {
        float v = xi[i];
        if (q) v = quant_comp_f(v);
        pin[i / 28 + 2][i % 28 + 2] = v;
    }
    __syncthreads();

    for (int item = t; item < 588; item += 256) {
        const int c = item / 98;
        const int rem = item % 98;
        const int ph = rem / 7;
        const int pw0 = 2 * (rem % 7);
        float wr[25];
        #pragma unroll
        for (int k = 0; k < 25; ++k) wr[k] = w1[c][k];
        float s[8];
        #pragma unroll
        for (int j = 0; j < 8; ++j) s[j] = 0.0f;
        const int oh = 2 * ph;
        const int ow = 2 * pw0;
        #pragma unroll
        for (int ky = 0; ky < 5; ++ky) {
            #pragma unroll
            for (int kx = 0; kx < 5; ++kx) {
                const float wv = wr[ky * 5 + kx];
                #pragma unroll
                for (int dy = 0; dy < 2; ++dy)
                    #pragma unroll
                    for (int dx = 0; dx < 4; ++dx)
                        s[dy * 4 + dx] = fmaf(pin[oh + dy + ky][ow + dx + kx], wv,
                                              s[dy * 4 + dx]);
            }
        }
        const float bb = b1s[c];
        float v[8];
        #pragma unroll
        for (int j = 0; j < 8; ++j) v[j] = s[j] + bb;
        float m0 = fmaxf(fmaxf(v[0], v[1]), fmaxf(v[4], v[5]));
        float m1 = fmaxf(fmaxf(v[2], v[3]), fmaxf(v[6], v[7]));
        m0 = fmaxf(m0, 0.0f); m1 = fmaxf(m1, 0.0f);
        if (q) { m0 = quant_comp_f(m0); m1 = quant_comp_f(m1); }
        mid[c][ph][pw0] = m0;
        mid[c][ph][pw0 + 1] = m1;
    }
    __syncthreads();

    float* ao = act + (size_t)img * 400;
    for (int item = t; item < 240; item += 256) {
        const int c = item / 15;
        const int rem = item % 15;
        const int ph = rem / 3;
        const int pj = rem % 3;
        const int pw0 = 2 * pj;
        float acc[2][4];
        #pragma unroll
        for (int dy = 0; dy < 2; ++dy)
            #pragma unroll
            for (int dx = 0; dx < 4; ++dx) acc[dy][dx] = 0.0f;
        #pragma unroll
        for (int ky = 0; ky < 5; ++ky) {
            #pragma unroll
            for (int kx = 0; kx < 5; ++kx) {
                #pragma unroll
                for (int ic = 0; ic < 6; ++ic) {
                    const float wv = w2[(c * 6 + ic) * 25 + ky * 5 + kx];
                    #pragma unroll
                    for (int dy = 0; dy < 2; ++dy)
                        #pragma unroll
                        for (int dx = 0; dx < 4; ++dx)
                            acc[dy][dx] = fmaf(mid[ic][2 * ph + dy + ky][2 * pw0 + dx + kx],
                                               wv, acc[dy][dx]);
                }
            }
        }
        const float bb = b2s[c];
        float v[2][4];
        #pragma unroll
        for (int dy = 0; dy < 2; ++dy)
            #pragma unroll
            for (int dx = 0; dx < 4; ++dx) v[dy][dx] = acc[dy][dx] + bb;
        float m0 = fmaxf(fmaxf(v[0][0], v[0][1]), fmaxf(v[1][0], v[1][1]));
        float m1 = fmaxf(fmaxf(v[0][2], v[0][3]), fmaxf(v[1][2], v[1][3]));
        m0 = fmaxf(m0, 0.0f); m1 = fmaxf(m1, 0.0f);
        if (q) { m0 = quant_comp_f(m0); m1 = quant_comp_f(m1); }
        const int o = c * 25 + ph * 5 + pw0;
        ao[o] = m0;
        if (pj < 2) ao[o + 1] = m1;
    }
}

__global__ __launch_bounds__(256) void fc_fused_kernel(
    const float* __restrict__ act,
    const float* __restrict__ w1, const float* __restrict__ b1,
    const float* __restrict__ w2, const float* __restrict__ b2,
    const float* __restrict__ w3, const float* __restrict__ b3,
    const int* __restrict__ qflag,
    float* __restrict__ out, int B, int gate)
{
    if (gate != 0 && qflag[0] != 0) return;
    __shared__ __align__(16) float a0[16][404];
    __shared__ __align__(16) float a1[16][124];
    __shared__ __align__(16) float a2[16][88];

    const int t = threadIdx.x;
    const bool q = (qflag[0] != 0);
    const int base = blockIdx.x * 16;

    for (int i = t; i < 16 * 400; i += 256) {
        const int im = i / 400, k = i % 400;
        if (base + im < B) a0[im][k] = act[(size_t)(base + im) * 400 + k];
    }
    __syncthreads();

    const int im = t & 15;
    const int grp = t >> 4;

    for (int o = grp; o < 120; o += 16) {
        const float4* wr = reinterpret_cast<const float4*>(w1 + o * 400);
        const float4* ar = reinterpret_cast<const float4*>(&a0[im][0]);
        float acc = 0.0f;
        #pragma unroll 4
        for (int kk = 0; kk < 100; ++kk) {
            const float4 av = ar[kk];
            const float4 wv = wr[kk];
            acc = fmaf(av.x, wv.x, acc);
            acc = fmaf(av.y, wv.y, acc);
            acc = fmaf(av.z, wv.z, acc);
            acc = fmaf(av.w, wv.w, acc);
        }
        float v = acc + b1[o];
        v = fmaxf(v, 0.0f);
        a1[im][o] = q ? quant_comp_f(v) : v;
    }
    __syncthreads();

    for (int o = grp; o < 84; o += 16) {
        const float4* wr = reinterpret_cast<const float4*>(w2 + o * 120);
        const float4* ar = reinterpret_cast<const float4*>(&a1[im][0]);
        float acc = 0.0f;
        #pragma unroll 4
        for (int kk = 0; kk < 30; ++kk) {
            const float4 av = ar[kk];
            const float4 wv = wr[kk];
            acc = fmaf(av.x, wv.x, acc);
            acc = fmaf(av.y, wv.y, acc);
            acc = fmaf(av.z, wv.z, acc);
            acc = fmaf(av.w, wv.w, acc);
        }
        float v = acc + b2[o];
        v = fmaxf(v, 0.0f);
        a2[im][o] = q ? quant_comp_f(v) : v;
    }
    __syncthreads();

    for (int o = grp; o < 10; o += 16) {
        const float4* wr = reinterpret_cast<const float4*>(w3 + o * 84);
        const float4* ar = reinterpret_cast<const float4*>(&a2[im][0]);
        float acc = 0.0f;
        #pragma unroll
        for (int kk = 0; kk < 21; ++kk) {
            const float4 av = ar[kk];
            const float4 wv = wr[kk];
            acc = fmaf(av.x, wv.x, acc);
            acc = fmaf(av.y, wv.y, acc);
            acc = fmaf(av.z, wv.z, acc);
            acc = fmaf(av.w, wv.w, acc);
        }
        if (base + im < B) out[(size_t)(base + im) * 10 + o] = acc + b3[o];
    }
}

extern "C" void kernel_launch(void* const* d_in, const int* in_sizes, int n_in,
                              void* d_out, int out_size, void* d_ws, size_t ws_size,
                              hipStream_t stream) {
    const float* x     = (const float*)d_in[0];
    const float* c1w   = (const float*)d_in[1];
    const float* c1b   = (const float*)d_in[2];
    const float* c2w   = (const float*)d_in[3];
    const float* c2b   = (const float*)d_in[4];
    const float* fc1w  = (const float*)d_in[5];
    const float* fc1b  = (const float*)d_in[6];
    const float* fc2w  = (const float*)d_in[7];
    const float* fc2b  = (const float*)d_in[8];
    const float* fc3w  = (const float*)d_in[9];
    const float* fc3b  = (const float*)d_in[10];
    const int*   qflag = (const int*)d_in[11];
    float* out = (float*)d_out;

    const int B = in_sizes[0] / 784;
    const int G = B / 64;
    char* ws = (char*)d_ws;

    // ws layout (bytes): mid8 [0, 19267584) ; xq8 [19267584, 32112640)
    //   act8 overlays xq8 head (6,553,600); a18 at +25,821,184 (1,966,080)
    //   weights at 32,112,640 (245,880). NEED = 32,358,520.
    const size_t NEED = 32358520;
    const bool np = (B % 64 == 0) && (ws_size >= NEED);

    if (np) {
        int8_t* mid8 = (int8_t*)ws;
        int8_t* xq8  = (int8_t*)(ws + 19267584);
        int8_t* act8 = (int8_t*)(ws + 19267584);
        int8_t* a18  = (int8_t*)(ws + 25821184);
        float* c1ws = (float*)(ws + 32112640);
        float* c2ws = (float*)(ws + 32112640 + 600);
        float* w1t  = (float*)(ws + 32112640 + 10200);
        float* w2t  = (float*)(ws + 32112640 + 202200);
        float* w3t  = (float*)(ws + 32112640 + 242520);

        prep_kernel<<<4099, 256, 0, stream>>>(x, c1w, c2w, fc1w, fc2w, fc3w,
                                              xq8, c1ws, c2ws, w1t, w2t, w3t,
                                              B * 784);
        conv1_int8_kernel<<<(G * 42 + 3) / 4, 256, 0, stream>>>(
            xq8, c1ws, c1b, qflag, mid8, G);
        conv2_int8_kernel<<<(G * 40 + 3) / 4, 256, 0, stream>>>(
            mid8, c2ws, c2b, qflag, act8, G);
        fc1_int8_kernel<<<2 * G, 256, 0, stream>>>(act8, w1t, fc1b, qflag, a18, G);
        fc23_int8_kernel<<<G, 256, 0, stream>>>(a18, w2t, fc2b, w3t, fc3b, qflag,
                                                out, G);
        // q==0 fallback (no-op when quantizing)
        float* actR4 = (float*)ws;
        conv_fused_kernel<<<B, 256, 0, stream>>>(x, c1w, c1b, c2w, c2b, qflag,
                                                 actR4, 1);
        fc_fused_kernel<<<(B + 15) / 16, 256, 0, stream>>>(
            actR4, fc1w, fc1b, fc2w, fc2b, fc3w, fc3b, qflag, out, B, 1);
    } else {
        float* actR4 = (float*)ws;
        conv_fused_kernel<<<B, 256, 0, stream>>>(x, c1w, c1b, c2w, c2b, qflag,
                                                 actR4, 0);
        fc_fused_kernel<<<(B + 15) / 16, 256, 0, stream>>>(
            actR4, fc1w, fc1b, fc2w, fc2b, fc3w, fc3b, qflag, out, B, 0);
    }
}